// Round 1
// baseline (111.089 us; speedup 1.0000x reference)
//
#include <hip/hip_runtime.h>

// Elementwise: out = (x*2+1)^2, fp32 in/out, 8192*8192 = 67,108,864 elements.
// Memory-bound: 512 MiB total traffic -> ~85us at 6.3 TB/s achievable.
// float4 vectorized grid-stride loop, 2048 blocks x 256 threads (G11/G13).

__global__ void fused_elemwise_f32(const float* __restrict__ in,
                                   float* __restrict__ out,
                                   long long n4) {
    long long idx = (long long)blockIdx.x * blockDim.x + threadIdx.x;
    long long stride = (long long)gridDim.x * blockDim.x;
    const float4* __restrict__ in4 = (const float4*)in;
    float4* __restrict__ out4 = (float4*)out;
    for (long long i = idx; i < n4; i += stride) {
        float4 v = in4[i];
        float4 r;
        float t0 = fmaf(v.x, 2.0f, 1.0f);
        float t1 = fmaf(v.y, 2.0f, 1.0f);
        float t2 = fmaf(v.z, 2.0f, 1.0f);
        float t3 = fmaf(v.w, 2.0f, 1.0f);
        r.x = t0 * t0;
        r.y = t1 * t1;
        r.z = t2 * t2;
        r.w = t3 * t3;
        out4[i] = r;
    }
}

// Tail kernel not needed (n % 4 == 0 for 8192*8192), but keep launch correct
// for any n: handle remainder with a tiny scalar pass if needed.
__global__ void fused_elemwise_f32_tail(const float* __restrict__ in,
                                        float* __restrict__ out,
                                        long long start, long long n) {
    long long i = start + (long long)blockIdx.x * blockDim.x + threadIdx.x;
    if (i < n) {
        float t = fmaf(in[i], 2.0f, 1.0f);
        out[i] = t * t;
    }
}

extern "C" void kernel_launch(void* const* d_in, const int* in_sizes, int n_in,
                              void* d_out, int out_size, void* d_ws, size_t ws_size,
                              hipStream_t stream) {
    const float* in = (const float*)d_in[0];
    float* out = (float*)d_out;
    long long n = (long long)in_sizes[0];
    long long n4 = n / 4;

    const int block = 256;
    int grid = (int)((n4 + block - 1) / block);
    if (grid > 2048) grid = 2048;
    if (grid < 1) grid = 1;

    fused_elemwise_f32<<<grid, block, 0, stream>>>(in, out, n4);

    long long rem_start = n4 * 4;
    if (rem_start < n) {
        long long rem = n - rem_start;
        int tgrid = (int)((rem + block - 1) / block);
        fused_elemwise_f32_tail<<<tgrid, block, 0, stream>>>(in, out, rem_start, n);
    }
}

// Round 2
// 88.956 us; speedup vs baseline: 1.2488x; 1.2488x over previous
//
#include <hip/hip_runtime.h>

// out = (x*2+1)^2, fp32, 8192*8192 = 67,108,864 elements = 16,777,216 float4.
// Pure streaming, 512 MiB total traffic. Target: ~6.3 TB/s achievable -> ~85us.
// R1: 4x float4 per thread (64B) for MLP + nontemporal load/store (no reuse,
// footprint > 256MiB L3). Exact-fit grid: 16384 blocks x 256 threads.

typedef float f32x4 __attribute__((ext_vector_type(4)));

__global__ void __launch_bounds__(256) fused_elemwise_x4(
    const f32x4* __restrict__ in4, f32x4* __restrict__ out4) {
    // Block handles 1024 contiguous float4s; lane-coalesced within each slice.
    long long base = (long long)blockIdx.x * 1024 + threadIdx.x;

    f32x4 a = __builtin_nontemporal_load(&in4[base]);
    f32x4 b = __builtin_nontemporal_load(&in4[base + 256]);
    f32x4 c = __builtin_nontemporal_load(&in4[base + 512]);
    f32x4 d = __builtin_nontemporal_load(&in4[base + 768]);

    #pragma unroll
    for (int j = 0; j < 4; ++j) {
        float t;
        t = fmaf(a[j], 2.0f, 1.0f); a[j] = t * t;
        t = fmaf(b[j], 2.0f, 1.0f); b[j] = t * t;
        t = fmaf(c[j], 2.0f, 1.0f); c[j] = t * t;
        t = fmaf(d[j], 2.0f, 1.0f); d[j] = t * t;
    }

    __builtin_nontemporal_store(a, &out4[base]);
    __builtin_nontemporal_store(b, &out4[base + 256]);
    __builtin_nontemporal_store(c, &out4[base + 512]);
    __builtin_nontemporal_store(d, &out4[base + 768]);
}

// Generic fallback for sizes not divisible by 4096 elements (not hit at 8192^2).
__global__ void fused_elemwise_tail(const float* __restrict__ in,
                                    float* __restrict__ out,
                                    long long start, long long n) {
    long long i = start + (long long)blockIdx.x * blockDim.x + threadIdx.x;
    if (i < n) {
        float t = fmaf(in[i], 2.0f, 1.0f);
        out[i] = t * t;
    }
}

extern "C" void kernel_launch(void* const* d_in, const int* in_sizes, int n_in,
                              void* d_out, int out_size, void* d_ws, size_t ws_size,
                              hipStream_t stream) {
    const float* in = (const float*)d_in[0];
    float* out = (float*)d_out;
    long long n = (long long)in_sizes[0];

    // Main kernel: each block covers 4096 elements (1024 float4).
    long long nblk = n / 4096;
    if (nblk > 0) {
        fused_elemwise_x4<<<(int)nblk, 256, 0, stream>>>(
            (const f32x4*)in, (f32x4*)out);
    }

    long long done = nblk * 4096;
    if (done < n) {
        long long rem = n - done;
        int tgrid = (int)((rem + 255) / 256);
        fused_elemwise_tail<<<tgrid, 256, 0, stream>>>(in, out, done, n);
    }
}